// Round 4
// baseline (192.201 us; speedup 1.0000x reference)
//
#include <hip/hip_runtime.h>

#define M_ANT 64
#define POWER_CONSTR 1.0f

typedef float f32x4 __attribute__((ext_vector_type(4)));

// ---------------------------------------------------------------------------
// Kernel 1: per-block partial energies per antenna — fully coalesced.
// float4 index f belongs to antenna (f>>2)&63; grid stride is a multiple of
// 256 float4s so each thread's antenna is FIXED. Lane i loads float4 at
// base+i -> 16B/lane coalesced. 8-deep unroll, 2 accumulators for MLP/ILP.
// Block combine: fixed-order LDS sum (deterministic, no float atomics).
// ---------------------------------------------------------------------------
__global__ __launch_bounds__(256) void energy_partial(
    const f32x4* __restrict__ P4, float* __restrict__ partials, int nvec) {
  const int tid = threadIdx.x;
  const int gtid = blockIdx.x * 256 + tid;
  const int stride = gridDim.x * 256;

  float acc0 = 0.0f, acc1 = 0.0f;
  int f = gtid;
  for (; f + 7 * stride < nvec; f += 8 * stride) {
    f32x4 v0 = P4[f];
    f32x4 v1 = P4[f + stride];
    f32x4 v2 = P4[f + 2 * stride];
    f32x4 v3 = P4[f + 3 * stride];
    f32x4 v4 = P4[f + 4 * stride];
    f32x4 v5 = P4[f + 5 * stride];
    f32x4 v6 = P4[f + 6 * stride];
    f32x4 v7 = P4[f + 7 * stride];
    acc0 += v0.x * v0.x + v0.y * v0.y + v0.z * v0.z + v0.w * v0.w;
    acc1 += v1.x * v1.x + v1.y * v1.y + v1.z * v1.z + v1.w * v1.w;
    acc0 += v2.x * v2.x + v2.y * v2.y + v2.z * v2.z + v2.w * v2.w;
    acc1 += v3.x * v3.x + v3.y * v3.y + v3.z * v3.z + v3.w * v3.w;
    acc0 += v4.x * v4.x + v4.y * v4.y + v4.z * v4.z + v4.w * v4.w;
    acc1 += v5.x * v5.x + v5.y * v5.y + v5.z * v5.z + v5.w * v5.w;
    acc0 += v6.x * v6.x + v6.y * v6.y + v6.z * v6.z + v6.w * v6.w;
    acc1 += v7.x * v7.x + v7.y * v7.y + v7.z * v7.z + v7.w * v7.w;
  }
  for (; f < nvec; f += stride) {
    f32x4 v = P4[f];
    acc0 += v.x * v.x + v.y * v.y + v.z * v.z + v.w * v.w;
  }

  __shared__ float part[256];
  part[tid] = acc0 + acc1;
  __syncthreads();
  if (tid < 64) {
    // threads 4a..4a+3 all hold antenna a
    float s = (part[4 * tid] + part[4 * tid + 1]) +
              (part[4 * tid + 2] + part[4 * tid + 3]);
    partials[blockIdx.x * 64 + tid] = s;
  }
}

// ---------------------------------------------------------------------------
// Kernel 2: reduce partials[nblocks][64] -> scale[64].
// 1 block x 1024 threads: thread (j=tid>>6, a=tid&63) sums blocks b===j (mod 16)
// -> coalesced 256B wave reads, 16-way MLP. Fixed-order LDS tree over j.
// ---------------------------------------------------------------------------
__global__ __launch_bounds__(1024) void energy_finalize(
    const float* __restrict__ partials, float* __restrict__ scale, int nblocks) {
  const int tid = threadIdx.x;
  const int a = tid & 63;
  const int j = tid >> 6;  // 0..15
  float s = 0.0f;
  for (int b = j; b < nblocks; b += 16) s += partials[b * 64 + a];
  __shared__ float part[1024];
  part[tid] = s;
  __syncthreads();
  if (tid < 512) part[tid] += part[tid + 512];
  __syncthreads();
  if (tid < 256) part[tid] += part[tid + 256];
  __syncthreads();
  if (tid < 128) part[tid] += part[tid + 128];
  __syncthreads();
  if (tid < 64) {
    const float energy = part[tid] + part[tid + 64];
    scale[tid] = sqrtf(POWER_CONSTR / energy);
  }
}

// ---------------------------------------------------------------------------
// Kernel 3: out = P * scale[antenna]. Coalesced float4 grid-stride; antenna
// fixed per thread. 8-deep unroll: 8 independent loads issued before the
// 8 scaled nt stores -> 8 KB/wave in flight. Non-temporal stores (output is
// never re-read; avoid evicting the L3-resident input).
// ---------------------------------------------------------------------------
__global__ __launch_bounds__(256) void apply_scale(
    const f32x4* __restrict__ P4, const float* __restrict__ scale,
    f32x4* __restrict__ O4, int nvec) {
  __shared__ float s_scale[M_ANT];
  if (threadIdx.x < M_ANT) s_scale[threadIdx.x] = scale[threadIdx.x];
  __syncthreads();

  const int gtid = blockIdx.x * 256 + threadIdx.x;
  const int stride = gridDim.x * 256;
  // antenna fixed per thread (stride multiple of 256 float4s)
  const float sc = s_scale[(threadIdx.x >> 2) & 63];

  int f = gtid;
  for (; f + 7 * stride < nvec; f += 8 * stride) {
    f32x4 v0 = P4[f];
    f32x4 v1 = P4[f + stride];
    f32x4 v2 = P4[f + 2 * stride];
    f32x4 v3 = P4[f + 3 * stride];
    f32x4 v4 = P4[f + 4 * stride];
    f32x4 v5 = P4[f + 5 * stride];
    f32x4 v6 = P4[f + 6 * stride];
    f32x4 v7 = P4[f + 7 * stride];
    __builtin_nontemporal_store(v0 * sc, &O4[f]);
    __builtin_nontemporal_store(v1 * sc, &O4[f + stride]);
    __builtin_nontemporal_store(v2 * sc, &O4[f + 2 * stride]);
    __builtin_nontemporal_store(v3 * sc, &O4[f + 3 * stride]);
    __builtin_nontemporal_store(v4 * sc, &O4[f + 4 * stride]);
    __builtin_nontemporal_store(v5 * sc, &O4[f + 5 * stride]);
    __builtin_nontemporal_store(v6 * sc, &O4[f + 6 * stride]);
    __builtin_nontemporal_store(v7 * sc, &O4[f + 7 * stride]);
  }
  for (; f < nvec; f += stride) {
    f32x4 v = P4[f];
    __builtin_nontemporal_store(v * sc, &O4[f]);
  }
}

extern "C" void kernel_launch(void* const* d_in, const int* in_sizes, int n_in,
                              void* d_out, int out_size, void* d_ws, size_t ws_size,
                              hipStream_t stream) {
  const f32x4* P4 = (const f32x4*)d_in[0];
  f32x4* O4 = (f32x4*)d_out;
  float* ws = (float*)d_ws;

  const int nelem = in_sizes[0];  // B * 2*M*K = 67,108,864
  const int nvec = nelem / 4;     // float4 count

  // Partial-reduction grid: 2048 blocks (8 blocks/CU), clamped to ws capacity.
  int nblocks1 = 2048;
  const size_t ws_floats = ws_size / sizeof(float);
  if (ws_floats < (size_t)nblocks1 * 64 + 64) {
    size_t cap = ws_floats > 64 ? (ws_floats - 64) / 64 : 1;
    nblocks1 = (int)(cap < 1 ? 1 : cap);
  }
  if (nblocks1 > (nvec + 255) / 256) nblocks1 = (nvec + 255) / 256;

  float* partials = ws;                       // nblocks1 * 64 floats
  float* scale = ws + (size_t)nblocks1 * 64;  // 64 floats

  energy_partial<<<nblocks1, 256, 0, stream>>>(P4, partials, nvec);
  energy_finalize<<<1, 1024, 0, stream>>>(partials, scale, nblocks1);

  int nblocks3 = (nvec + 255) / 256;
  if (nblocks3 > 2048) nblocks3 = 2048;
  apply_scale<<<nblocks3, 256, 0, stream>>>(P4, scale, O4, nvec);
}